// Round 4
// baseline (554.828 us; speedup 1.0000x reference)
//
#include <hip/hip_runtime.h>

typedef _Float16 f16;
typedef _Float16 f16x2 __attribute__((ext_vector_type(2)));
typedef _Float16 f16x4 __attribute__((ext_vector_type(4)));
typedef _Float16 f16x8 __attribute__((ext_vector_type(8)));
typedef float f32x4 __attribute__((ext_vector_type(4)));

__device__ __forceinline__ f32x4 mfma16(f16x8 a, f16x8 b, f32x4 c) {
  return __builtin_amdgcn_mfma_f32_16x16x32_f16(a, b, c, 0, 0, 0);
}

__device__ __forceinline__ float sigmoid_(float x) { return 1.f / (1.f + __expf(-x)); }
__device__ __forceinline__ float tanh_(float x) { return 1.f - 2.f / (__expf(2.f * x) + 1.f); }

// ---------------------------------------------------------------------------
// fused fp32 -> fp16 conversion of W_vt, W_ih, W_hh (one launch)
// ---------------------------------------------------------------------------
__global__ void cvt3_kernel(const float* __restrict__ s0, f16* __restrict__ d0, int n0,
                            const float* __restrict__ s1, f16* __restrict__ d1, int n1,
                            const float* __restrict__ s2, f16* __restrict__ d2, int n2) {
  int i = blockIdx.x * 256 + threadIdx.x;
  const float* s;
  f16* d;
  int j;
  if (i < n0) {
    s = s0; d = d0; j = i;
  } else if (i < n0 + n1) {
    s = s1; d = d1; j = i - n0;
  } else if (i < n0 + n1 + n2) {
    s = s2; d = d2; j = i - n0 - n1;
  } else {
    return;
  }
  float4 v = ((const float4*)s)[j];
  f16x4 h = {(f16)v.x, (f16)v.y, (f16)v.z, (f16)v.w};
  ((f16x4*)d)[j] = h;
}

// ---------------------------------------------------------------------------
// GEMM1: P[split][2048][512] (f16 partials) = v[2048,20000] @ W_down^T slabs.
// A and B both fp32 in HBM, converted to f16 during staging. 128x128 tiles,
// k-split 16 -> 1024 blocks (>=3/CU, launch_bounds(256,3)): TLP covers the
// L3-hit latency that capped R2 at 2 blocks/CU. LDS stride 44 f16: staging
// writes 2-way (free), frag reads spread over 16 banks.
// XCD = linear%8 = split%8 keeps each k-slab of W_down L2-resident (2.56 MB).
// ---------------------------------------------------------------------------
__global__ __launch_bounds__(256, 3) void gemm1_kernel(
    const float* __restrict__ A, const float* __restrict__ B, f16* __restrict__ P) {
  constexpr int K = 20000;
  __shared__ f16 Al[128][44];
  __shared__ f16 Bl[128][44];
  int tid = threadIdx.x;
  int split = blockIdx.x;  // 0..15
  int m0 = (blockIdx.y >> 2) * 128, n0 = (blockIdx.y & 3) * 128;
  int it0 = (split * 625) >> 4, it1 = ((split + 1) * 625) >> 4;
  int wid = tid >> 6, lane = tid & 63;
  int wm = wid & 1, wn = wid >> 1;
  int lm = lane & 15, quad = lane >> 4;
  int srow = tid >> 1, sseg = (tid & 1) * 16;  // 16 fp32 cols per thread

  const float* aptr = A + (size_t)(m0 + srow) * K + sseg;
  const float* bptr = B + (size_t)(n0 + srow) * K + sseg;

  float4 Ar[4], Br[4];
  {
    int k0 = it0 * 32;
#pragma unroll
    for (int j = 0; j < 4; ++j) {
      Ar[j] = *(const float4*)(aptr + k0 + j * 4);
      Br[j] = *(const float4*)(bptr + k0 + j * 4);
    }
  }

  f32x4 acc[4][4];
#pragma unroll
  for (int i = 0; i < 4; ++i)
#pragma unroll
    for (int j = 0; j < 4; ++j) acc[i][j] = (f32x4){0.f, 0.f, 0.f, 0.f};

  for (int it = it0; it < it1; ++it) {
    __syncthreads();
    {
      f16x8 pa0 = {(f16)Ar[0].x, (f16)Ar[0].y, (f16)Ar[0].z, (f16)Ar[0].w,
                   (f16)Ar[1].x, (f16)Ar[1].y, (f16)Ar[1].z, (f16)Ar[1].w};
      f16x8 pa1 = {(f16)Ar[2].x, (f16)Ar[2].y, (f16)Ar[2].z, (f16)Ar[2].w,
                   (f16)Ar[3].x, (f16)Ar[3].y, (f16)Ar[3].z, (f16)Ar[3].w};
      f16x8 pb0 = {(f16)Br[0].x, (f16)Br[0].y, (f16)Br[0].z, (f16)Br[0].w,
                   (f16)Br[1].x, (f16)Br[1].y, (f16)Br[1].z, (f16)Br[1].w};
      f16x8 pb1 = {(f16)Br[2].x, (f16)Br[2].y, (f16)Br[2].z, (f16)Br[2].w,
                   (f16)Br[3].x, (f16)Br[3].y, (f16)Br[3].z, (f16)Br[3].w};
      *(f16x8*)&Al[srow][sseg] = pa0;
      *(f16x8*)&Al[srow][sseg + 8] = pa1;
      *(f16x8*)&Bl[srow][sseg] = pb0;
      *(f16x8*)&Bl[srow][sseg + 8] = pb1;
    }
    if (it + 1 < it1) {  // prefetch next k-tile; consumed after next barrier+MFMA
      int kn = (it + 1) * 32;
#pragma unroll
      for (int j = 0; j < 4; ++j) {
        Ar[j] = *(const float4*)(aptr + kn + j * 4);
        Br[j] = *(const float4*)(bptr + kn + j * 4);
      }
    }
    __syncthreads();
    f16x8 af[4];
#pragma unroll
    for (int mi = 0; mi < 4; ++mi) af[mi] = *(const f16x8*)&Al[wm * 64 + mi * 16 + lm][quad * 8];
#pragma unroll
    for (int ni = 0; ni < 4; ++ni) {
      f16x8 bf = *(const f16x8*)&Bl[wn * 64 + ni * 16 + lm][quad * 8];
#pragma unroll
      for (int mi = 0; mi < 4; ++mi) acc[mi][ni] = mfma16(af[mi], bf, acc[mi][ni]);
    }
  }
  size_t base = (size_t)split * 2048;
#pragma unroll
  for (int mi = 0; mi < 4; ++mi)
#pragma unroll
    for (int ni = 0; ni < 4; ++ni)
#pragma unroll
      for (int r = 0; r < 4; ++r) {
        int row = m0 + wm * 64 + mi * 16 + quad * 4 + r;
        int col = n0 + wn * 64 + ni * 16 + lm;
        P[(base + row) * 512 + col] = (f16)acc[mi][ni][r];
      }
}

// ---------------------------------------------------------------------------
// build vt[2048,640] f16 = [ sum_16 P | t*Wt_up_w + Wt_up_b ]
// ---------------------------------------------------------------------------
__global__ void build_vt_kernel(const f16* __restrict__ P, const float* __restrict__ t,
                                const float* __restrict__ wtw, const float* __restrict__ wtb,
                                f16* __restrict__ vt) {
  int m = blockIdx.x;
  float tv = t[m];
  for (int c = threadIdx.x; c < 640; c += 256) {
    float val;
    if (c < 512) {
      val = 0.f;
#pragma unroll
      for (int s = 0; s < 16; ++s) val += (float)P[((size_t)s * 2048 + m) * 512 + c];
    } else {
      val = tv * wtw[c - 512] + wtb[c - 512];
    }
    vt[(size_t)m * 640 + c] = (f16)val;
  }
}

// ---------------------------------------------------------------------------
// Tiled fp16 GEMM template: C[M,N] = A[M,K] @ Bt[N,K]^T (both K-contiguous).
// TM,TN in {64,128}; wave grid 2x2. EPI 0: plain f16 store. EPI 1: xg layout
// (row m -> l=m&15, b=m>>4 swap) + bias add.
// ---------------------------------------------------------------------------
template <int TM, int TN, int EPI>
__global__ __launch_bounds__(256, 4) void gemmT_kernel(
    const f16* __restrict__ A, const f16* __restrict__ B, f16* __restrict__ out,
    const float* __restrict__ bias0, const float* __restrict__ bias1, int K_iters, int K,
    int N) {
  constexpr int FM = TM / 32, FN = TN / 32;
  __shared__ f16 Al[TM][40];
  __shared__ f16 Bl[TN][40];
  int tid = threadIdx.x;
  int m0 = blockIdx.y * TM, n0 = blockIdx.x * TN;
  int wid = tid >> 6, lane = tid & 63;
  int wm = wid & 1, wn = wid >> 1;
  int lm = lane & 15, quad = lane >> 4;

  f32x4 acc[FM][FN];
#pragma unroll
  for (int i = 0; i < FM; ++i)
#pragma unroll
    for (int j = 0; j < FN; ++j) acc[i][j] = (f32x4){0.f, 0.f, 0.f, 0.f};

  for (int it = 0; it < K_iters; ++it) {
    int k0 = it * 32;
    __syncthreads();
#pragma unroll
    for (int r = 0; r < TM / 64; ++r) {
      int slot = r * 256 + tid;
      int row = slot >> 2, seg = slot & 3;
      *(f16x8*)&Al[row][seg * 8] = *(const f16x8*)(A + (size_t)(m0 + row) * K + k0 + seg * 8);
    }
#pragma unroll
    for (int r = 0; r < TN / 64; ++r) {
      int slot = r * 256 + tid;
      int row = slot >> 2, seg = slot & 3;
      *(f16x8*)&Bl[row][seg * 8] = *(const f16x8*)(B + (size_t)(n0 + row) * K + k0 + seg * 8);
    }
    __syncthreads();
    f16x8 af[FM];
#pragma unroll
    for (int mi = 0; mi < FM; ++mi)
      af[mi] = *(const f16x8*)&Al[wm * (TM / 2) + mi * 16 + lm][quad * 8];
#pragma unroll
    for (int ni = 0; ni < FN; ++ni) {
      f16x8 bf = *(const f16x8*)&Bl[wn * (TN / 2) + ni * 16 + lm][quad * 8];
#pragma unroll
      for (int mi = 0; mi < FM; ++mi) acc[mi][ni] = mfma16(af[mi], bf, acc[mi][ni]);
    }
  }
#pragma unroll
  for (int mi = 0; mi < FM; ++mi)
#pragma unroll
    for (int ni = 0; ni < FN; ++ni)
#pragma unroll
      for (int r = 0; r < 4; ++r) {
        int row = m0 + wm * (TM / 2) + mi * 16 + quad * 4 + r;
        int col = n0 + wn * (TN / 2) + ni * 16 + lm;
        float val = acc[mi][ni][r];
        if (EPI == 0) {
          out[(size_t)row * N + col] = (f16)val;
        } else {
          int l = row & 15, b = row >> 4;
          out[(size_t)(l * 128 + b) * N + col] = (f16)(val + bias0[col] + bias1[col]);
        }
      }
}

// ---------------------------------------------------------------------------
// LSTM step (one launch per step; kernel boundary = the barrier).
// Grid (64 hid-slices, 4 batch-slices) = 256 blocks. Block = 256 thr, wave = gate.
// h-slice [32][1024] staged once into LDS; W_hh B-frags from L2 with 8-deep
// register ring prefetch; c transposed [hid][batch] f32; h out via LDS bounce.
// ---------------------------------------------------------------------------
__global__ __launch_bounds__(256, 1) void lstm_step2_kernel(
    const f16* __restrict__ h_in, const f16* __restrict__ Whh,
    const f16* __restrict__ xg_l, float* __restrict__ cT, f16* __restrict__ h_out) {
  __shared__ f16 Alf[32 * 1032];   // h slice, +8 f16 pad per row
  __shared__ float gl[4][32][17];  // gate exchange
  __shared__ f16 hx[32][18];       // h-out bounce
  int tid = threadIdx.x;
  int w = tid >> 6, lane = tid & 63;
  int lm = lane & 15, quad = lane >> 4;
  int h0 = blockIdx.x * 16;  // hid base
  int b0 = blockIdx.y * 32;  // batch base

#pragma unroll
  for (int i = 0; i < 16; ++i) {
    int idx = i * 256 + tid;
    int r = idx >> 7, c8 = (idx & 127) * 8;
    *(f16x8*)&Alf[r * 1032 + c8] = *(const f16x8*)(h_in + (size_t)(b0 + r) * 1024 + c8);
  }
  const f16* wrow = Whh + ((size_t)(w << 10) + h0 + lm) * 1024 + quad * 8;
  f16x8 Bv[8];
#pragma unroll
  for (int j = 0; j < 8; ++j) Bv[j] = *(const f16x8*)(wrow + j * 32);
  f32x4 acc0 = {0.f, 0.f, 0.f, 0.f}, acc1 = {0.f, 0.f, 0.f, 0.f};
  __syncthreads();
#pragma unroll
  for (int it = 0; it < 32; ++it) {
    f16x8 bfr = Bv[it & 7];
    if (it < 24) Bv[it & 7] = *(const f16x8*)(wrow + (it + 8) * 32);
    f16x8 a0 = *(const f16x8*)&Alf[lm * 1032 + it * 32 + quad * 8];
    f16x8 a1 = *(const f16x8*)&Alf[(16 + lm) * 1032 + it * 32 + quad * 8];
    acc0 = mfma16(a0, bfr, acc0);
    acc1 = mfma16(a1, bfr, acc1);
  }
#pragma unroll
  for (int r = 0; r < 4; ++r) {
    gl[w][quad * 4 + r][lm] = acc0[r];
    gl[w][16 + quad * 4 + r][lm] = acc1[r];
  }
  __syncthreads();
#pragma unroll
  for (int half = 0; half < 2; ++half) {
    int b = tid & 31, hl = (tid >> 5) + half * 8;
    int gb = b0 + b, gh = h0 + hl;
    const f16* xr = xg_l + (size_t)gb * 4096 + gh;
    float gi = (float)xr[0] + gl[0][b][hl];
    float gf = (float)xr[1024] + gl[1][b][hl];
    float gg = (float)xr[2048] + gl[2][b][hl];
    float go = (float)xr[3072] + gl[3][b][hl];
    float iv = sigmoid_(gi), fv = sigmoid_(gf), gv = tanh_(gg), ov = sigmoid_(go);
    size_t ci = (size_t)gh * 128 + gb;
    float cc = fv * cT[ci] + iv * gv;
    cT[ci] = cc;
    hx[b][hl] = (f16)(ov * tanh_(cc));
  }
  __syncthreads();
  {
    int b = tid >> 3, e = (tid & 7) * 2;
    f16x2 hv = {hx[b][e], hx[b][e + 1]};
    *(f16x2*)(h_out + (size_t)(b0 + b) * 1024 + h0 + e) = hv;
  }
}

// ---------------------------------------------------------------------------
// pred[b] = dot(h[b] (f16), lin_w) + lin_b
// ---------------------------------------------------------------------------
__global__ void pred_kernel(const f16* __restrict__ h, const float* __restrict__ w,
                            const float* __restrict__ b, float* __restrict__ out) {
  int bb = blockIdx.x, tid = threadIdx.x;
  f16x4 hv = *(const f16x4*)(h + (size_t)bb * 1024 + tid * 4);
  float4 wv = *(const float4*)(w + tid * 4);
  float s = (float)hv[0] * wv.x + (float)hv[1] * wv.y + (float)hv[2] * wv.z + (float)hv[3] * wv.w;
#pragma unroll
  for (int off = 32; off > 0; off >>= 1) s += __shfl_down(s, off);
  __shared__ float red[4];
  if ((tid & 63) == 0) red[tid >> 6] = s;
  __syncthreads();
  if (tid == 0) out[bb] = red[0] + red[1] + red[2] + red[3] + b[0];
}

// ---------------------------------------------------------------------------
extern "C" void kernel_launch(void* const* d_in, const int* in_sizes, int n_in,
                              void* d_out, int out_size, void* d_ws, size_t ws_size,
                              hipStream_t stream) {
  (void)in_sizes; (void)n_in; (void)out_size; (void)ws_size;
  const float* v      = (const float*)d_in[0];
  const float* t      = (const float*)d_in[1];
  const float* W_down = (const float*)d_in[2];
  const float* Wt_w   = (const float*)d_in[3];
  const float* Wt_b   = (const float*)d_in[4];
  const float* W_vt   = (const float*)d_in[5];
  const float* W_ih   = (const float*)d_in[6];
  const float* W_hh   = (const float*)d_in[7];
  const float* b_ih   = (const float*)d_in[8];
  const float* b_hh   = (const float*)d_in[9];
  const float* lin_w  = (const float*)d_in[10];
  const float* lin_b  = (const float*)d_in[11];

  char* ws = (char*)d_ws;
  constexpr size_t OFF_WVT = 0;         //    655,360 : W_vt f16 [512][640]
  constexpr size_t OFF_WIH = 655360;    //  4,194,304 : W_ih f16 [4096][512]
  constexpr size_t OFF_WHH = 4849664;   //  8,388,608 : W_hh f16 [4096][1024]
  constexpr size_t OFF_VT  = 13238272;  //  2,621,440 : vt   f16 [2048][640]
  constexpr size_t OFF_IN  = 15859712;  //  2,097,152 : inputs f16 [2048][512]
  constexpr size_t OFF_P   = 17956864;  // 33,554,432 : P f16 [16][2048][512], then xg f16 [16][128][4096] overlays
  constexpr size_t OFF_H0  = 51511296;  //    262,144 : h ping f16
  constexpr size_t OFF_C   = 51773440;  //    524,288 : c_T f32 [1024][128] (adjacent to H0: one memset)
  constexpr size_t OFF_H1  = 52297728;  //    262,144 : h pong f16 (fully written at s=0)
  // total 52,559,872 B < 56.3 MB proven available in R1/R2

  f16* wvt16  = (f16*)(ws + OFF_WVT);
  f16* wih16  = (f16*)(ws + OFF_WIH);
  f16* whh16  = (f16*)(ws + OFF_WHH);
  f16* vt16   = (f16*)(ws + OFF_VT);
  f16* in16   = (f16*)(ws + OFF_IN);
  f16* pxg    = (f16*)(ws + OFF_P);
  float* cT   = (float*)(ws + OFF_C);
  f16* hb[2]  = {(f16*)(ws + OFF_H0), (f16*)(ws + OFF_H1)};

  hipMemsetAsync(ws + OFF_H0, 0, 786432, stream);  // h0 + c_T

  // W_vt: 81920 float4, W_ih: 524288, W_hh: 1048576 -> 1,654,784 total
  cvt3_kernel<<<6465, 256, 0, stream>>>(W_vt, wvt16, 81920, W_ih, wih16, 524288, W_hh, whh16,
                                        1048576);

  gemm1_kernel<<<dim3(16, 64), 256, 0, stream>>>(v, W_down, pxg);
  build_vt_kernel<<<2048, 256, 0, stream>>>(pxg, t, Wt_w, Wt_b, vt16);
  // inputs[2048,512] = vt @ W_vt^T : K=640
  gemmT_kernel<64, 64, 0><<<dim3(8, 32), 256, 0, stream>>>(vt16, wvt16, in16, nullptr, nullptr,
                                                           20, 640, 512);
  // xg[16][128][4096] = inputs @ W_ih^T + b : K=512
  gemmT_kernel<64, 128, 1><<<dim3(32, 32), 256, 0, stream>>>(in16, wih16, pxg, b_ih, b_hh, 16,
                                                             512, 4096);

  for (int s = 0; s < 16; ++s) {
    lstm_step2_kernel<<<dim3(64, 4), 256, 0, stream>>>(
        hb[s & 1], whh16, pxg + (size_t)s * 128 * 4096, cT, hb[(s + 1) & 1]);
  }
  pred_kernel<<<128, 256, 0, stream>>>(hb[0], lin_w, lin_b, (float*)d_out);
}